// Round 6
// baseline (577.545 us; speedup 1.0000x reference)
//
#include <hip/hip_runtime.h>

#define NN 8192
#define DIM 64
#define NR 5
#define BM 256      // output rows per block
#define BK 512      // K window per block = 16 ktiles of 32

typedef __attribute__((ext_vector_type(8))) short short8;
typedef __attribute__((ext_vector_type(4))) float f32x4;

__device__ inline unsigned short f2bf(float x) {
    unsigned u = __float_as_uint(x);
    return (unsigned short)((u + 0x7FFFu + ((u >> 16) & 1u)) >> 16);
}

// P fragment linear index (shorts) for (r, k, o).
// Bijection within a ktile: g=(k>>3)&3, j=k&7. A-mask build uses the same
// (g,j)->k map, so the permutation cancels inside the MFMA.
__device__ inline int pfrag_idx(int r, int k, int o) {
    int ktile = k >> 5;
    int g     = (k >> 3) & 3;
    int j     = k & 7;
    int lane  = g * 16 + (o & 15);
    int n     = o >> 4;
    return ((r * (NN / 32) + ktile) * 4 + n) * 512 + lane * 8 + j;
}

// ---------------- zero-init (R4-verified; replaces pathological rocclr fill) --
__global__ __launch_bounds__(256) void zero_k(float* __restrict__ outp,
                                              unsigned* __restrict__ deg)
{
    const int stride = gridDim.x * blockDim.x;
    int i = blockIdx.x * blockDim.x + threadIdx.x;
    int4 z = {0, 0, 0, 0};
    for (int idx = i; idx < 2 * NN * DIM / 4; idx += stride) ((int4*)outp)[idx] = z;
    for (int idx = i; idx < 2 * NN / 4; idx += stride) ((int4*)deg)[idx] = z;
}

// ---------------- P precompute: P[r][v][o] = sum_f feat[v][f] * W[r][f][o] ----
__global__ __launch_bounds__(256) void precompute_P(
    const float* __restrict__ u_feat, const float* __restrict__ v_feat,
    const float* __restrict__ w_u, const float* __restrict__ w_v,
    unsigned short* __restrict__ p_u, unsigned short* __restrict__ p_v)
{
    int wid  = (blockIdx.x * blockDim.x + threadIdx.x) >> 6;
    int lane = threadIdx.x & 63;
    const int tasks = 2 * NR * (NN / 32);
    if (wid >= tasks) return;
    int dir  = wid / (NR * (NN / 32));
    int rem  = wid % (NR * (NN / 32));
    int r    = rem / (NN / 32);
    int v0   = (rem % (NN / 32)) * 32;

    const float* feat = dir ? u_feat : v_feat;
    const float* w    = dir ? w_v : w_u;
    unsigned short* dst = dir ? p_v : p_u;

    float wreg[DIM];
#pragma unroll
    for (int f = 0; f < DIM; ++f) wreg[f] = w[(r * DIM + f) * DIM + lane];

    for (int v = v0; v < v0 + 32; ++v) {
        float x = feat[(size_t)v * DIM + lane];
        float acc = 0.f;
#pragma unroll
        for (int f = 0; f < DIM; ++f) acc += __shfl(x, f) * wreg[f];
        dst[pfrag_idx(r, v, lane)] = f2bf(acc);
    }
}

// ---------------- masked GEMM (R3 structure + 4 m-tiles/wave, K-phase split) --
// Nibble tile[row][256B], swizzle: dword d stored at d^(row&31).
// Wave w: m-group = w&3 (rows (w&3)*64..+63), K-phase = w>>2 (even/odd ktiles).
// Each ktile's B read by 4 waves (was 8) -> B L2 traffic halved vs R3.
// K-phase pair folded via tile reused as f32[256][64] with n^g col swizzle.
template <int TRANS>
__global__ __launch_bounds__(512, 4) void gemm_masked(
    const int* __restrict__ adj, const unsigned short* __restrict__ pfrag,
    float* __restrict__ outp, unsigned int* __restrict__ deg)
{
    __shared__ unsigned char tile[BM][256];   // 64 KB
    __shared__ unsigned int  cnt[BM];         // TRANS==0 degree counts
    __shared__ unsigned int  sc2[512];        // TRANS==1 packed degree partials

    const int tid  = threadIdx.x;
    const int lane = tid & 63;
    const int wv   = tid >> 6;
    const int b0   = blockIdx.x * BM;         // output-row base
    const int k0   = blockIdx.y * BK;         // K base

    unsigned cpack = 0;

    // ================= staging (R3-verified) =================
    if (TRANS == 0) {
        int4 pre[4], nxt[4];
        const int sub = tid & 31;             // 32 threads per row
        auto issue = [&](int rnd, int4* dst) {
            int row = rnd * 16 + (tid >> 5);
            const int* base = adj + (size_t)(b0 + row) * NN + k0 + sub * 4;
#pragma unroll
            for (int it = 0; it < 4; ++it) dst[it] = *(const int4*)(base + it * 128);
        };
        issue(0, pre);
        for (int rnd = 0; rnd < 16; ++rnd) {
            if (rnd + 1 < 16) issue(rnd + 1, nxt);
            int row = rnd * 16 + (tid >> 5);
            unsigned lo = 0, hi = 0;
#pragma unroll
            for (int it = 0; it < 4; ++it) {
                int4 a = pre[it];
                unsigned long long bx = __ballot(a.x != 0), by = __ballot(a.y != 0);
                unsigned long long bz = __ballot(a.z != 0), bw = __ballot(a.w != 0);
                lo += __popcll(bx & 0xFFFFFFFFull) + __popcll(by & 0xFFFFFFFFull) +
                      __popcll(bz & 0xFFFFFFFFull) + __popcll(bw & 0xFFFFFFFFull);
                hi += __popcll(bx >> 32) + __popcll(by >> 32) +
                      __popcll(bz >> 32) + __popcll(bw >> 32);
                unsigned pk = (unsigned)a.x | ((unsigned)a.y << 4) |
                              ((unsigned)a.z << 8) | ((unsigned)a.w << 12);
                int d  = it * 16 + (sub >> 1);
                int dp = d ^ (row & 31);
                *(unsigned short*)&tile[row][dp * 4 + (sub & 1) * 2] = (unsigned short)pk;
            }
            if ((tid & 31) == 0) cnt[row] = (lane & 32) ? hi : lo;
#pragma unroll
            for (int it = 0; it < 4; ++it) pre[it] = nxt[it];
        }
    } else {
        const int v4 = (tid & 63) * 4;
        int4 pre[4], nxt[4];
        auto issue = [&](int rnd, int4* dst) {
            int u0 = rnd * 32 + (tid >> 6) * 4;
#pragma unroll
            for (int c = 0; c < 4; ++c)
                dst[c] = *(const int4*)(adj + (size_t)(k0 + u0 + c) * NN + b0 + v4);
        };
        issue(0, pre);
        for (int rnd = 0; rnd < 16; ++rnd) {
            if (rnd + 1 < 16) issue(rnd + 1, nxt);
            const int* q0 = (const int*)&pre[0]; const int* q1 = (const int*)&pre[1];
            const int* q2 = (const int*)&pre[2]; const int* q3 = (const int*)&pre[3];
            int d    = rnd * 4 + ((tid >> 6) >> 1);
            int half = (tid >> 6) & 1;
#pragma unroll
            for (int cc = 0; cc < 4; ++cc) {
                int x0 = q0[cc], x1 = q1[cc], x2 = q2[cc], x3 = q3[cc];
                unsigned pk = (unsigned)x0 | ((unsigned)x1 << 4) |
                              ((unsigned)x2 << 8) | ((unsigned)x3 << 12);
                int row = v4 + cc;
                int dp  = d ^ (row & 31);
                *(unsigned short*)&tile[row][dp * 4 + half * 2] = (unsigned short)pk;
                cpack += (unsigned)((x0 != 0) + (x1 != 0) + (x2 != 0) + (x3 != 0)) << (8 * cc);
            }
#pragma unroll
            for (int c = 0; c < 4; ++c) pre[c] = nxt[c];
        }
        sc2[tid] = cpack;
    }
    __syncthreads();

    const unsigned* t32 = (const unsigned*)&tile[0][0];
    const int mgrp = wv & 3;          // rows mgrp*64 .. +63
    const int ph   = wv >> 2;         // K phase: even/odd ktiles
    const int g    = lane >> 4;
    const int c15  = lane & 15;

    f32x4 acc[4][4];
#pragma unroll
    for (int m = 0; m < 4; ++m)
#pragma unroll
        for (int n = 0; n < 4; ++n) acc[m][n] = (f32x4){0.f, 0.f, 0.f, 0.f};

    for (int s = ph; s < 16; s += 2) {
        unsigned nib[4];
#pragma unroll
        for (int m = 0; m < 4; ++m) {
            int row = mgrp * 64 + m * 16 + c15;
            int d   = s * 4 + g;
            nib[m] = t32[row * 64 + (d ^ (row & 31))];
        }
        const int ktg = (k0 >> 5) + s;
#pragma unroll
        for (int r = 0; r < NR; ++r) {
            short8 bf[4];
#pragma unroll
            for (int n = 0; n < 4; ++n)
                bf[n] = *(const short8*)(pfrag +
                         ((size_t)(r * (NN / 32) + ktg) * 4 + n) * 512 + lane * 8);
#pragma unroll
            for (int m = 0; m < 4; ++m) {
                short8 am;
#pragma unroll
                for (int j = 0; j < 8; ++j)
                    am[j] = (short)(((nib[m] >> (4 * j)) & 0xFu) == (unsigned)(r + 1) ? 0x3F80 : 0);
#pragma unroll
                for (int n = 0; n < 4; ++n)
                    acc[m][n] = __builtin_amdgcn_mfma_f32_16x16x32_bf16(am, bf[n], acc[m][n], 0, 0, 0);
            }
        }
    }

    // ---- K-phase fold through tile-as-f32 (n^g col swizzle: conflict-free) ----
    __syncthreads();
    float* lf = (float*)&tile[0][0];
    if (wv >= 4) {
#pragma unroll
        for (int m = 0; m < 4; ++m)
#pragma unroll
            for (int n = 0; n < 4; ++n)
#pragma unroll
                for (int q = 0; q < 4; ++q)
                    lf[(mgrp * 64 + m * 16 + g * 4 + q) * 64 + ((n ^ g) * 16 + c15)] = acc[m][n][q];
    }
    __syncthreads();
    if (wv < 4) {
#pragma unroll
        for (int m = 0; m < 4; ++m) {
#pragma unroll
            for (int n = 0; n < 4; ++n)
#pragma unroll
                for (int q = 0; q < 4; ++q) {
                    int rl = mgrp * 64 + m * 16 + g * 4 + q;
                    float sum = acc[m][n][q] + lf[rl * 64 + ((n ^ g) * 16 + c15)];
                    atomicAdd(&outp[(size_t)(b0 + rl) * DIM + n * 16 + c15], sum);
                }
        }
    }

    // ---- degree reductions ----
    if (TRANS == 0) {
        if (tid < BM) atomicAdd(&deg[b0 + tid], cnt[tid]);
    } else {
        if (tid < BM) {
            unsigned tot = 0;
            int base = tid >> 2, byte = tid & 3;
#pragma unroll
            for (int j = 0; j < 8; ++j) tot += (sc2[j * 64 + base] >> (8 * byte)) & 0xFFu;
            atomicAdd(&deg[b0 + tid], tot);
        }
    }
}

// ---------------- finalize: scale by 1/deg, ReLU ----------------
__global__ __launch_bounds__(256) void finalize_k(
    float* __restrict__ outp, const unsigned int* __restrict__ deg_u,
    const unsigned int* __restrict__ deg_v)
{
    int idx = blockIdx.x * blockDim.x + threadIdx.x;
    const int total = 2 * NN * DIM;
    for (; idx < total; idx += gridDim.x * blockDim.x) {
        int row = idx >> 6;
        unsigned d = (row < NN) ? deg_u[row] : deg_v[row - NN];
        float s = d ? (1.f / (float)d) : 0.f;
        float v = outp[idx] * s;
        outp[idx] = v > 0.f ? v : 0.f;
    }
}

extern "C" void kernel_launch(void* const* d_in, const int* in_sizes, int n_in,
                              void* d_out, int out_size, void* d_ws, size_t ws_size,
                              hipStream_t stream)
{
    const int*   adj = (const int*)d_in[0];
    const float* uf  = (const float*)d_in[1];
    const float* vf  = (const float*)d_in[2];
    const float* wu  = (const float*)d_in[3];
    const float* wv  = (const float*)d_in[4];
    float* outp = (float*)d_out;

    unsigned char* ws = (unsigned char*)d_ws;
    const size_t P_BYTES = (size_t)NR * (NN / 32) * 4 * 64 * 8 * 2;  // 5,242,880
    unsigned short* p_u = (unsigned short*)ws;
    unsigned short* p_v = (unsigned short*)(ws + P_BYTES);
    unsigned int*   deg = (unsigned int*)(ws + 2 * P_BYTES);   // deg_u | deg_v

    zero_k<<<1024, 256, 0, stream>>>(outp, deg);
    precompute_P<<<640, 256, 0, stream>>>(uf, vf, wu, wv, p_u, p_v);

    dim3 grid(NN / BM, NN / BK);
    gemm_masked<0><<<grid, 512, 0, stream>>>(adj, p_u, outp, deg);
    gemm_masked<1><<<grid, 512, 0, stream>>>(adj, p_v, outp + (size_t)NN * DIM, deg + NN);

    finalize_k<<<2048, 256, 0, stream>>>(outp, deg, deg + NN);
}

// Round 7
// 282.744 us; speedup vs baseline: 2.0426x; 2.0426x over previous
//
#include <hip/hip_runtime.h>

#define N_U 8192
#define N_V 8192
#define DIM 64
#define NR 5
#define BM 256      // M rows per block
#define BK 512      // K window per block = 16 ktiles of 32
#define NSTEP 16

typedef __attribute__((ext_vector_type(8))) short short8;
typedef __attribute__((ext_vector_type(4))) float f32x4;

__device__ inline unsigned short f2bf(float x) {
    unsigned u = __float_as_uint(x);
    return (unsigned short)((u + 0x7FFFu + ((u >> 16) & 1u)) >> 16);
}

// P fragment linear index (shorts) for (r, k, o).
// Bijection within a ktile: g = (k>>3)&3, j = k&7 (k = g*8+j). Same map is
// used for the A-mask build, so the permutation cancels in the MFMA.
__device__ inline size_t pfrag_idx(int r, int k, int o) {
    int ktile = k >> 5;
    int g     = (k >> 3) & 3;
    int j     = k & 7;
    int lane  = g * 16 + (o & 15);
    int n     = o >> 4;
    return ((((size_t)r * (N_V / 32) + ktile) * 4 + n) * 64 + lane) * 8 + j;
}

// ---------------- zero-init (replaces pathological rocclr fill) ----------------
__global__ __launch_bounds__(256) void zero_k(float* __restrict__ outp,
                                              unsigned* __restrict__ deg)
{
    const int stride = gridDim.x * blockDim.x;
    int i = blockIdx.x * blockDim.x + threadIdx.x;
    int4 z = {0, 0, 0, 0};
    for (int idx = i; idx < 2 * N_U * DIM / 4; idx += stride) ((int4*)outp)[idx] = z;
    for (int idx = i; idx < (N_U + N_V) / 4; idx += stride) ((int4*)deg)[idx] = z;
}

// ---------------- P precompute: P[r][v][o] = sum_f feat[v][f] * W[r][f][o] ----
__global__ __launch_bounds__(256) void precompute_P(
    const float* __restrict__ u_feat, const float* __restrict__ v_feat,
    const float* __restrict__ w_u, const float* __restrict__ w_v,
    unsigned short* __restrict__ p_u, unsigned short* __restrict__ p_v)
{
    int wid  = (blockIdx.x * blockDim.x + threadIdx.x) >> 6;
    int lane = threadIdx.x & 63;
    const int tasks = 2 * NR * (N_V / 32);
    if (wid >= tasks) return;
    int dir  = wid / (NR * (N_V / 32));
    int rem  = wid % (NR * (N_V / 32));
    int r    = rem / (N_V / 32);
    int v0   = (rem % (N_V / 32)) * 32;

    const float* feat = dir ? u_feat : v_feat;
    const float* w    = dir ? w_v : w_u;
    unsigned short* dst = dir ? p_v : p_u;

    float wreg[DIM];
#pragma unroll
    for (int f = 0; f < DIM; ++f) wreg[f] = w[(r * DIM + f) * DIM + lane];

    for (int v = v0; v < v0 + 32; ++v) {
        float x = feat[(size_t)v * DIM + lane];
        float acc = 0.f;
#pragma unroll
        for (int f = 0; f < DIM; ++f) acc += __shfl(x, f) * wreg[f];
        dst[pfrag_idx(r, v, lane)] = f2bf(acc);
    }
}

// ---------------- masked GEMM (R3-verified): nibble tile resident in LDS -----
// out[row][o] += sum_r sum_k (adj==r+1)[row][k] * P[r][k][o]
// TRANS=0: row=u, k=v (2KB-contiguous row reads). TRANS=1: row=v, k=u (4x4 transpose).
// 512 thr = 8 waves; wave owns 32 rows (2 m-tiles) x all 4 n-slices.
// LDS nibble tile [256][256B], XOR swizzle d^=(row&31). No barriers in main loop.
template <int TRANS>
__global__ __launch_bounds__(512, 4) void gemm_masked(
    const int* __restrict__ adj, const unsigned short* __restrict__ pfrag,
    float* __restrict__ outp, unsigned int* __restrict__ deg)
{
    __shared__ unsigned char tile[BM][256];   // 64 KB
    __shared__ unsigned int  cnt[BM];

    const int tid  = threadIdx.x;
    const int lane = tid & 63;
    const int wv   = tid >> 6;
    const int b0   = blockIdx.x * BM;
    const int k0   = blockIdx.y * BK;

    unsigned cpack = 0;   // TRANS=1 per-thread packed byte counters

    // ================= staging =================
    if (TRANS == 0) {
        int4 pre[4], nxt[4];
        const int sub = tid & 31;            // 32 threads per row
        auto issue = [&](int rnd, int4* dst) {
            int row = rnd * 16 + (tid >> 5);
            const int* base = adj + (size_t)(b0 + row) * N_V + k0 + sub * 4;
#pragma unroll
            for (int it = 0; it < 4; ++it) dst[it] = *(const int4*)(base + it * 128);
        };
        issue(0, pre);
        for (int rnd = 0; rnd < 16; ++rnd) {
            if (rnd + 1 < 16) issue(rnd + 1, nxt);
            int row = rnd * 16 + (tid >> 5);
            unsigned lo = 0, hi = 0;
#pragma unroll
            for (int it = 0; it < 4; ++it) {
                int4 a = pre[it];
                unsigned long long bx = __ballot(a.x != 0), by = __ballot(a.y != 0);
                unsigned long long bz = __ballot(a.z != 0), bw = __ballot(a.w != 0);
                lo += __popcll(bx & 0xFFFFFFFFull) + __popcll(by & 0xFFFFFFFFull) +
                      __popcll(bz & 0xFFFFFFFFull) + __popcll(bw & 0xFFFFFFFFull);
                hi += __popcll(bx >> 32) + __popcll(by >> 32) +
                      __popcll(bz >> 32) + __popcll(bw >> 32);
                unsigned pk = (unsigned)a.x | ((unsigned)a.y << 4) |
                              ((unsigned)a.z << 8) | ((unsigned)a.w << 12);
                int d  = it * 16 + (sub >> 1);
                int dp = d ^ (row & 31);
                *(unsigned short*)&tile[row][dp * 4 + (sub & 1) * 2] = (unsigned short)pk;
            }
            if ((tid & 31) == 0) cnt[row] = (lane & 32) ? hi : lo;
#pragma unroll
            for (int it = 0; it < 4; ++it) pre[it] = nxt[it];
        }
    } else {
        const int v4 = (tid & 63) * 4;
        int4 pre[4], nxt[4];
        auto issue = [&](int rnd, int4* dst) {
            int u0 = rnd * 32 + (tid >> 6) * 4;
#pragma unroll
            for (int c = 0; c < 4; ++c)
                dst[c] = *(const int4*)(adj + (size_t)(k0 + u0 + c) * N_V + b0 + v4);
        };
        issue(0, pre);
        for (int rnd = 0; rnd < 16; ++rnd) {
            if (rnd + 1 < 16) issue(rnd + 1, nxt);
            const int* q0 = (const int*)&pre[0]; const int* q1 = (const int*)&pre[1];
            const int* q2 = (const int*)&pre[2]; const int* q3 = (const int*)&pre[3];
            int d    = rnd * 4 + ((tid >> 6) >> 1);
            int half = (tid >> 6) & 1;
#pragma unroll
            for (int cc = 0; cc < 4; ++cc) {
                int x0 = q0[cc], x1 = q1[cc], x2 = q2[cc], x3 = q3[cc];
                unsigned pk = (unsigned)x0 | ((unsigned)x1 << 4) |
                              ((unsigned)x2 << 8) | ((unsigned)x3 << 12);
                int row = v4 + cc;
                int dp  = d ^ (row & 31);
                *(unsigned short*)&tile[row][dp * 4 + half * 2] = (unsigned short)pk;
                cpack += (unsigned)((x0 != 0) + (x1 != 0) + (x2 != 0) + (x3 != 0)) << (8 * cc);
            }
#pragma unroll
            for (int c = 0; c < 4; ++c) pre[c] = nxt[c];
        }
    }
    __syncthreads();

    // ================= main loop: no barriers =================
    f32x4 acc[2][4];
#pragma unroll
    for (int m = 0; m < 2; ++m)
#pragma unroll
        for (int n = 0; n < 4; ++n) acc[m][n] = (f32x4){0.f, 0.f, 0.f, 0.f};

    const int mrow = wv * 32;
    for (int s = 0; s < NSTEP; ++s) {
        unsigned nib[2];
#pragma unroll
        for (int m = 0; m < 2; ++m) {
            int row = mrow + m * 16 + (lane & 15);
            int d   = s * 4 + (lane >> 4);
            nib[m] = *(const unsigned*)&tile[row][((d ^ (row & 31)) << 2)];
        }
        const int ktg = (k0 >> 5) + s;
#pragma unroll
        for (int r = 0; r < NR; ++r) {
            short8 bf[4];
#pragma unroll
            for (int n = 0; n < 4; ++n)
                bf[n] = *(const short8*)(pfrag +
                         ((((size_t)r * (N_V / 32) + ktg) * 4 + n) * 64 + lane) * 8);
            short8 am[2];
#pragma unroll
            for (int m = 0; m < 2; ++m)
#pragma unroll
                for (int j = 0; j < 8; ++j) {
                    unsigned nb = (nib[m] >> (4 * j)) & 0xFu;
                    am[m][j] = (short)(nb == (unsigned)(r + 1) ? 0x3F80 : 0);
                }
#pragma unroll
            for (int n = 0; n < 4; ++n) {
                acc[0][n] = __builtin_amdgcn_mfma_f32_16x16x32_bf16(am[0], bf[n], acc[0][n], 0, 0, 0);
                acc[1][n] = __builtin_amdgcn_mfma_f32_16x16x32_bf16(am[1], bf[n], acc[1][n], 0, 0, 0);
            }
        }
    }

    // ================= epilogue =================
    // C layout: col = lane&15, row = (lane>>4)*4 + q
#pragma unroll
    for (int m = 0; m < 2; ++m) {
        int rbase = b0 + mrow + m * 16 + ((lane >> 4) << 2);
#pragma unroll
        for (int n = 0; n < 4; ++n)
#pragma unroll
            for (int q = 0; q < 4; ++q)
                atomicAdd(&outp[(size_t)(rbase + q) * DIM + n * 16 + (lane & 15)], acc[m][n][q]);
    }

    if (TRANS == 0) {
        if (tid < BM) atomicAdd(&deg[b0 + tid], cnt[tid]);
    } else {
        __syncthreads();
        unsigned* sc = (unsigned*)&tile[0][0];
        sc[tid] = cpack;
        __syncthreads();
        if (tid < BM) {
            unsigned tot = 0;
            int base = tid >> 2, byte = tid & 3;
#pragma unroll
            for (int j = 0; j < 8; ++j) tot += (sc[j * 64 + base] >> (8 * byte)) & 0xFFu;
            atomicAdd(&deg[b0 + tid], tot);
        }
    }
}

// ---------------- finalize: scale by 1/deg, ReLU ----------------
__global__ __launch_bounds__(256) void finalize_k(
    float* __restrict__ outp, const unsigned int* __restrict__ deg_u,
    const unsigned int* __restrict__ deg_v)
{
    int idx = blockIdx.x * blockDim.x + threadIdx.x;
    const int total = 2 * N_U * DIM;
    for (; idx < total; idx += gridDim.x * blockDim.x) {
        int row = idx >> 6;
        unsigned d = (row < N_U) ? deg_u[row] : deg_v[row - N_U];
        float s = d ? (1.f / (float)d) : 0.f;
        float v = outp[idx] * s;
        outp[idx] = v > 0.f ? v : 0.f;
    }
}

extern "C" void kernel_launch(void* const* d_in, const int* in_sizes, int n_in,
                              void* d_out, int out_size, void* d_ws, size_t ws_size,
                              hipStream_t stream)
{
    const int*   adj = (const int*)d_in[0];
    const float* uf  = (const float*)d_in[1];
    const float* vf  = (const float*)d_in[2];
    const float* wu  = (const float*)d_in[3];
    const float* wv  = (const float*)d_in[4];
    float* outp = (float*)d_out;

    unsigned char* ws = (unsigned char*)d_ws;
    const size_t P_BYTES = (size_t)NR * (N_V / 32) * 4 * 64 * 8 * 2;  // 5,242,880
    unsigned short* p_u = (unsigned short*)ws;
    unsigned short* p_v = (unsigned short*)(ws + P_BYTES);
    unsigned int*   deg = (unsigned int*)(ws + 2 * P_BYTES);   // deg_u | deg_v

    zero_k<<<1024, 256, 0, stream>>>(outp, deg);
    precompute_P<<<640, 256, 0, stream>>>(uf, vf, wu, wv, p_u, p_v);

    dim3 grid(N_U / BM, N_V / BK);
    gemm_masked<0><<<grid, 512, 0, stream>>>(adj, p_u, outp, deg);
    gemm_masked<1><<<grid, 512, 0, stream>>>(adj, p_v, outp + (size_t)N_U * DIM, deg + N_U);

    finalize_k<<<2048, 256, 0, stream>>>(outp, deg, deg + N_U);
}